// Round 4
// baseline (271.915 us; speedup 1.0000x reference)
//
#include <hip/hip_runtime.h>

// Problem constants (fixed by the reference):
#define B_ 8
#define S_ 8192
#define H_ 512
#define D_ 768
#define P_ 128

#define NWT   96                      // W-transpose blocks (dispatched first)
#define NPOOL (P_ * B_)               // 1024 pool blocks
#define NGEMM ((D_ / 64) * ((B_ * P_) / 64))  // 192 gemm tiles (12 x 16)

typedef __attribute__((ext_vector_type(8))) short bf16x8;   // 8 bf16 (4 VGPRs)
typedef __attribute__((ext_vector_type(4))) float f32x4;    // MFMA C/D

// fp32 -> bf16 round-to-nearest-even
static __device__ inline unsigned short f2bf(float f) {
    unsigned int u = __float_as_uint(f);
    unsigned int r = (u + 0x7fffu + ((u >> 16) & 1u)) >> 16;
    return (unsigned short)r;
}

// ws layout: means_bf16 [B*P][H] (1 MiB) | Wt_bf16 [D][H] (0.75 MiB) |
//            pflag[1024] | wflag[96]  (flags re-poisoned by harness each iter)

// ---------------------------------------------------------------------------
// Single fused kernel. Blocks [0,96): W transpose+convert; [96,1120): pool;
// [1120,1312): GEMM tiles that spin on device-scope flags for exactly the
// 64 means-rows + 8 Wt-slices they consume. Producers publish with
// __syncthreads() (drain all waves' stores) -> __threadfence() (agent fence,
// L2 writeback: per-XCD L2s are NOT coherent) -> relaxed agent flag store.
// Consumers: relaxed agent polls + __syncthreads_and, then one acquire
// __threadfence() (invalidate stale L1/L2 lines from the previous graph
// iteration) before touching data. Flag values 0xA3000000+i / 0xB4000000+j:
// no uniform-byte poison can match them.
// Deadlock-free: 36.9 KB LDS -> 4 blocks/CU = 1024 resident slots; <=192
// spinners always leave >=832 slots for producer blocks (which never wait).
// ---------------------------------------------------------------------------
__global__ __launch_bounds__(256) void fused_kernel(
    const float* __restrict__ bh, const int* __restrict__ ids,
    const float* __restrict__ W, const float* __restrict__ bias,
    unsigned short* __restrict__ means, unsigned short* __restrict__ Wt,
    int* __restrict__ pflag, int* __restrict__ wflag,
    float* __restrict__ C)
{
    // union of: pool scratch (9216 B) | wt tile (9216 B) | gemm As+Bs (36864 B)
    __shared__ __align__(16) char smem[36864];
    const int bid = blockIdx.x;
    const int t = threadIdx.x;

    if (bid < NWT) {
        // ---------------- W transpose+convert (first: Wt ready early) -------
        const int id = bid;                 // 0..95
        const int nb = (id % (D_ / 64)) * 64;
        const int kb = (id / (D_ / 64)) * 64;
        unsigned short (*T)[72] = (unsigned short (*)[72])smem;  // [n][k]
        {
            const int kk = t >> 4;         // 0..15
            const int nn = (t & 15) * 4;   // 0..60
            #pragma unroll
            for (int i = 0; i < 4; ++i) {
                float4 v = *(const float4*)&W[(size_t)(kb + kk + i * 16) * D_ + nb + nn];
                T[nn + 0][kk + i * 16] = f2bf(v.x);
                T[nn + 1][kk + i * 16] = f2bf(v.y);
                T[nn + 2][kk + i * 16] = f2bf(v.z);
                T[nn + 3][kk + i * 16] = f2bf(v.w);
            }
        }
        __syncthreads();
        {
            const int nn = t >> 4;
            const int kk = (t & 15) * 4;
            #pragma unroll
            for (int i = 0; i < 4; ++i) {
                ushort4 o;
                o.x = T[nn + i * 16][kk + 0];
                o.y = T[nn + i * 16][kk + 1];
                o.z = T[nn + i * 16][kk + 2];
                o.w = T[nn + i * 16][kk + 3];
                *(ushort4*)&Wt[(size_t)(nb + nn + i * 16) * H_ + kb + kk] = o;
            }
        }
        __syncthreads();                    // all waves' Wt stores drained
        if (t == 0) {
            __threadfence();                // agent release: L2 writeback
            __hip_atomic_store(&wflag[id], 0xB4000000 + id,
                               __ATOMIC_RELAXED, __HIP_MEMORY_SCOPE_AGENT);
        }
    } else if (bid < NWT + NPOOL) {
        // ---------------- pool ---------------------------------------------
        const int pb = bid - NWT;
        const int p = pb & (P_ - 1);
        const int b = pb >> 7;
        const int c = t & 127;
        const int r_ofs = t >> 7;

        const int* row = ids + (size_t)b * S_;

        // sampled bracket: one parallel probe round, then 5 serial levels
        const int v = row[t * 32];                    // t*32 <= 8160 < S_
        const unsigned long long bal0 = __ballot(v < p);
        const unsigned long long bal1 = __ballot(v <= p);
        int* cnts = (int*)(smem + 2048);
        if ((t & 63) == 0) {
            cnts[t >> 6]       = __popcll(bal0);
            cnts[4 + (t >> 6)] = __popcll(bal1);
        }
        __syncthreads();
        const int c0 = cnts[0] + cnts[1] + cnts[2] + cnts[3];
        const int c1 = cnts[4] + cnts[5] + cnts[6] + cnts[7];

        int lo0 = c0 ? 32 * (c0 - 1) + 1 : 0, hi0 = 32 * c0;
        int lo1 = c1 ? 32 * (c1 - 1) + 1 : 0, hi1 = 32 * c1;
        #pragma unroll
        for (int it = 0; it < 5; ++it) {
            int m0 = (lo0 + hi0) >> 1; if (m0 > S_ - 1) m0 = S_ - 1;
            int m1 = (lo1 + hi1) >> 1; if (m1 > S_ - 1) m1 = S_ - 1;
            int v0 = row[m0], v1 = row[m1];
            if (v0 < p)  lo0 = m0 + 1; else hi0 = m0;
            if (v1 <= p) lo1 = m1 + 1; else hi1 = m1;
        }
        const int start = lo0;
        const int cnt   = lo1 - lo0;

        // streaming: measured loop (unroll-2, 2 accumulators)
        const float4* src = (const float4*)(bh + ((size_t)b * S_ + (size_t)start) * H_) + c;
        float4 a0 = {0.f, 0.f, 0.f, 0.f};
        float4 a1 = {0.f, 0.f, 0.f, 0.f};
        int r = r_ofs;
        for (; r + 2 < cnt; r += 4) {
            float4 v0 = src[(size_t)r * (H_ / 4)];
            float4 v1 = src[(size_t)(r + 2) * (H_ / 4)];
            a0.x += v0.x; a0.y += v0.y; a0.z += v0.z; a0.w += v0.w;
            a1.x += v1.x; a1.y += v1.y; a1.z += v1.z; a1.w += v1.w;
        }
        if (r < cnt) {
            float4 v2 = src[(size_t)r * (H_ / 4)];
            a0.x += v2.x; a0.y += v2.y; a0.z += v2.z; a0.w += v2.w;
        }
        float4 s;
        s.x = a0.x + a1.x; s.y = a0.y + a1.y; s.z = a0.z + a1.z; s.w = a0.w + a1.w;

        float4* red = (float4*)smem;  // 2 KB
        if (r_ofs == 1) red[c] = s;
        __syncthreads();
        if (r_ofs == 0) {
            float4 o = red[c];
            const float inv = 1.0f / (float)(cnt > 0 ? cnt : 1);
            ushort4 w;
            w.x = f2bf((s.x + o.x) * inv);
            w.y = f2bf((s.y + o.y) * inv);
            w.z = f2bf((s.z + o.z) * inv);
            w.w = f2bf((s.w + o.w) * inv);
            *(ushort4*)&means[((size_t)pb) * H_ + c * 4] = w;
        }
        __syncthreads();                    // all waves' means stores drained
        if (t == 0) {
            __threadfence();                // agent release: L2 writeback
            __hip_atomic_store(&pflag[pb], 0xA3000000 + pb,
                               __ATOMIC_RELAXED, __HIP_MEMORY_SCOPE_AGENT);
        }
    } else {
        // ---------------- GEMM tile ----------------------------------------
        // C[64x64] = means @ Wt^T + bias via mfma_f32_16x16x32_bf16.
        // Ping-pong dbuf LDS, one barrier per K-step (round-3-measured body).
        const int g  = bid - (NWT + NPOOL);
        const int gx = g % (D_ / 64);       // n-tile 0..11
        const int gy = g / (D_ / 64);       // m-tile 0..15
        const int m0 = gy * 64;
        const int n0 = gx * 64;

        // wait for the 64 means rows + 8 Wt k-slices this tile consumes
        {
            const int* fp = nullptr;
            int exp = 0;
            if (t < 64)      { fp = pflag + m0 + t;            exp = 0xA3000000 + m0 + t; }
            else if (t < 72) { int j = gx + (D_ / 64) * (t - 64);
                               fp = wflag + j;                 exp = 0xB4000000 + j; }
            for (;;) {
                int ok = 1;
                if (fp) ok = (__hip_atomic_load(fp, __ATOMIC_RELAXED,
                                                __HIP_MEMORY_SCOPE_AGENT) == exp);
                if (__syncthreads_and(ok)) break;
                __builtin_amdgcn_s_sleep(2);
            }
            __threadfence();                // agent acquire: invalidate stale L1/L2
        }

        unsigned short (*As)[64][72] = (unsigned short (*)[64][72])smem;
        unsigned short (*Bs)[64][72] = (unsigned short (*)[64][72])(smem + 18432);

        const int lane = t & 63;
        const int wv   = t >> 6;
        const int mrow = lane & 15;
        const int quad = lane >> 4;

        const int sr = t >> 2;
        const int sk = (t & 3) * 16;
        const unsigned short* Aptr = means + (size_t)(m0 + sr) * H_ + sk;
        const unsigned short* Bptr = Wt    + (size_t)(n0 + sr) * H_ + sk;

        uint4 a0 = *(const uint4*)Aptr;
        uint4 a1 = *(const uint4*)(Aptr + 8);
        uint4 b0 = *(const uint4*)Bptr;
        uint4 b1 = *(const uint4*)(Bptr + 8);

        *(uint4*)&As[0][sr][sk]     = a0;
        *(uint4*)&As[0][sr][sk + 8] = a1;
        *(uint4*)&Bs[0][sr][sk]     = b0;
        *(uint4*)&Bs[0][sr][sk + 8] = b1;

        f32x4 acc[4] = {};
        int cur = 0;
        __syncthreads();

        for (int k0 = 0; k0 < H_; k0 += 64) {
            const bool more = (k0 + 64 < H_);
            if (more) {
                a0 = *(const uint4*)(Aptr + k0 + 64);
                a1 = *(const uint4*)(Aptr + k0 + 72);
                b0 = *(const uint4*)(Bptr + k0 + 64);
                b1 = *(const uint4*)(Bptr + k0 + 72);
            }

            #pragma unroll
            for (int kk = 0; kk < 2; ++kk) {
                bf16x8 af = *(const bf16x8*)&As[cur][wv * 16 + mrow][kk * 32 + quad * 8];
                #pragma unroll
                for (int t4 = 0; t4 < 4; ++t4) {
                    bf16x8 bf = *(const bf16x8*)&Bs[cur][t4 * 16 + mrow][kk * 32 + quad * 8];
                    acc[t4] = __builtin_amdgcn_mfma_f32_16x16x32_bf16(af, bf, acc[t4], 0, 0, 0);
                }
            }

            if (more) {  // write OTHER buffer: disjoint from this step's reads
                *(uint4*)&As[cur ^ 1][sr][sk]     = a0;
                *(uint4*)&As[cur ^ 1][sr][sk + 8] = a1;
                *(uint4*)&Bs[cur ^ 1][sr][sk]     = b0;
                *(uint4*)&Bs[cur ^ 1][sr][sk + 8] = b1;
                __syncthreads();   // publish for next step; the ONLY barrier/step
            }
            cur ^= 1;
        }

        #pragma unroll
        for (int t4 = 0; t4 < 4; ++t4) {
            const int col = n0 + t4 * 16 + mrow;
            const float bia = bias[col];
            #pragma unroll
            for (int r = 0; r < 4; ++r) {
                const int rowi = m0 + wv * 16 + quad * 4 + r;
                C[(size_t)rowi * D_ + col] = acc[t4][r] + bia;
            }
        }
    }
}

extern "C" void kernel_launch(void* const* d_in, const int* in_sizes, int n_in,
                              void* d_out, int out_size, void* d_ws, size_t ws_size,
                              hipStream_t stream) {
    const float* bh   = (const float*)d_in[0];
    const float* W    = (const float*)d_in[1];
    const float* bias = (const float*)d_in[2];
    const int*   ids  = (const int*)d_in[3];
    float* out = (float*)d_out;

    unsigned short* means = (unsigned short*)d_ws;                    // 1 MiB
    unsigned short* Wt    = means + (size_t)B_ * P_ * H_;             // 0.75 MiB
    int* pflag = (int*)(Wt + (size_t)D_ * H_);                        // 4 KiB
    int* wflag = pflag + NPOOL;                                       // 384 B

    fused_kernel<<<dim3(NWT + NPOOL + NGEMM), 256, 0, stream>>>(      // 1312 blocks
        bh, ids, W, bias, means, Wt, pflag, wflag, out);
}

// Round 5
// 205.232 us; speedup vs baseline: 1.3249x; 1.3249x over previous
//
#include <hip/hip_runtime.h>

// Problem constants (fixed by the reference):
#define B_ 8
#define S_ 8192
#define H_ 512
#define D_ 768
#define P_ 128

typedef __attribute__((ext_vector_type(8))) short bf16x8;   // 8 bf16 (4 VGPRs)
typedef __attribute__((ext_vector_type(4))) float f32x4;    // MFMA C/D

// fp32 -> bf16 round-to-nearest-even
static __device__ inline unsigned short f2bf(float f) {
    unsigned int u = __float_as_uint(f);
    unsigned int r = (u + 0x7fffu + ((u >> 16) & 1u)) >> 16;
    return (unsigned short)r;
}

// ws layout: means_bf16 [B*P][H] (1 MiB) | Wt_bf16 [D][H] (0.75 MiB)

// ---------------------------------------------------------------------------
// Fused kernel 1: blocks [0,2048) do per-(b,p,half) mean pooling (each
// (b,p) segment split into two COLUMN halves -> disjoint means writes, no
// combining); blocks [2048,2144) transpose+convert W fp32 -> Wt_bf16.
// 2048 pool blocks x 4 waves = 8192 waves = exactly full machine occupancy
// (256 CU x 32 waves); halving per-block work halves tail imbalance.
//
// Segment lookup (unchanged, measured): 256-sample parallel bracket
// (thread t probes row[t*32]; ballot+popc per wave, LDS combine) narrows
// both lower_bounds to a 31-wide window, then 5 serial levels. m clamped
// to S-1 makes converged iterations no-ops -> fixed unroll safe.
// Streaming: thread (t&63) owns float4-column (t&63)+half*64; r_ofs=t>>6
// strides rows by 4, two loads in flight (r, r+4), step 8.
// ---------------------------------------------------------------------------
__global__ __launch_bounds__(256) void pool_wt_kernel(
    const float* __restrict__ bh, const int* __restrict__ ids,
    const float* __restrict__ W,
    unsigned short* __restrict__ means, unsigned short* __restrict__ Wt)
{
    __shared__ __align__(16) char smem[64 * 72 * sizeof(unsigned short)];
    const int bid = blockIdx.x;
    const int t = threadIdx.x;

    if (bid < 2 * P_ * B_) {
        // ---------------- pool (column-half block) ----------------
        const int pb   = bid >> 1;          // (b,p) segment 0..1023
        const int half = bid & 1;           // column half 0/1
        const int p = pb & (P_ - 1);
        const int b = pb >> 7;
        const int c  = (t & 63) + half * 64;  // float4 column 0..127
        const int r_ofs = t >> 6;             // 0..3

        const int* row = ids + (size_t)b * S_;

        // --- sampled bracket: one parallel probe round ---
        const int v = row[t * 32];                    // t*32 <= 8160 < S_
        const unsigned long long bal0 = __ballot(v < p);
        const unsigned long long bal1 = __ballot(v <= p);
        int* cnts = (int*)(smem + 4096);              // beyond the 4 KB red area
        if ((t & 63) == 0) {
            cnts[t >> 6]       = __popcll(bal0);
            cnts[4 + (t >> 6)] = __popcll(bal1);
        }
        __syncthreads();
        const int c0 = cnts[0] + cnts[1] + cnts[2] + cnts[3];
        const int c1 = cnts[4] + cnts[5] + cnts[6] + cnts[7];

        // lower_bound(p) in [lo0,hi0], lower_bound(p+1) in [lo1,hi1]; width <= 31
        int lo0 = c0 ? 32 * (c0 - 1) + 1 : 0, hi0 = 32 * c0;
        int lo1 = c1 ? 32 * (c1 - 1) + 1 : 0, hi1 = 32 * c1;
        #pragma unroll
        for (int it = 0; it < 5; ++it) {
            int m0 = (lo0 + hi0) >> 1; if (m0 > S_ - 1) m0 = S_ - 1;
            int m1 = (lo1 + hi1) >> 1; if (m1 > S_ - 1) m1 = S_ - 1;
            int v0 = row[m0], v1 = row[m1];
            if (v0 < p)  lo0 = m0 + 1; else hi0 = m0;
            if (v1 <= p) lo1 = m1 + 1; else hi1 = m1;
        }
        const int start = lo0;
        const int cnt   = lo1 - lo0;

        // --- streaming: rows strided by 4 over r_ofs, 2 loads in flight ---
        const float4* src = (const float4*)(bh + ((size_t)b * S_ + (size_t)start) * H_) + c;
        float4 a0 = {0.f, 0.f, 0.f, 0.f};
        float4 a1 = {0.f, 0.f, 0.f, 0.f};
        int r = r_ofs;
        for (; r + 4 < cnt; r += 8) {
            float4 v0 = src[(size_t)r * (H_ / 4)];
            float4 v1 = src[(size_t)(r + 4) * (H_ / 4)];
            a0.x += v0.x; a0.y += v0.y; a0.z += v0.z; a0.w += v0.w;
            a1.x += v1.x; a1.y += v1.y; a1.z += v1.z; a1.w += v1.w;
        }
        if (r < cnt) {  // at most one leftover row per thread (r+4 >= cnt here)
            float4 v2 = src[(size_t)r * (H_ / 4)];
            a0.x += v2.x; a0.y += v2.y; a0.z += v2.z; a0.w += v2.w;
        }
        float4 s;
        s.x = a0.x + a1.x; s.y = a0.y + a1.y; s.z = a0.z + a1.z; s.w = a0.w + a1.w;

        // reduce over the 4 r_ofs groups: groups 1..3 park in LDS, group 0 adds
        float4* red = (float4*)smem;  // 3 x 64 float4 = 3 KB (within 4 KB area)
        if (r_ofs > 0) red[(r_ofs - 1) * 64 + (t & 63)] = s;
        __syncthreads();
        if (r_ofs == 0) {
            float4 o0 = red[(t & 63)];
            float4 o1 = red[64 + (t & 63)];
            float4 o2 = red[128 + (t & 63)];
            const float inv = 1.0f / (float)(cnt > 0 ? cnt : 1);
            ushort4 w;
            w.x = f2bf((s.x + o0.x + o1.x + o2.x) * inv);
            w.y = f2bf((s.y + o0.y + o1.y + o2.y) * inv);
            w.z = f2bf((s.z + o0.z + o1.z + o2.z) * inv);
            w.w = f2bf((s.w + o0.w + o1.w + o2.w) * inv);
            *(ushort4*)&means[((size_t)pb) * H_ + c * 4] = w;
        }
    } else {
        // ---------------- W transpose+convert ----------------
        const int id = bid - 2 * P_ * B_;   // 0..95
        const int nb = (id % (D_ / 64)) * 64;
        const int kb = (id / (D_ / 64)) * 64;
        unsigned short (*T)[72] = (unsigned short (*)[72])smem;  // [n][k]
        {
            const int kk = t >> 4;         // 0..15
            const int nn = (t & 15) * 4;   // 0..60
            #pragma unroll
            for (int i = 0; i < 4; ++i) {
                float4 v = *(const float4*)&W[(size_t)(kb + kk + i * 16) * D_ + nb + nn];
                T[nn + 0][kk + i * 16] = f2bf(v.x);
                T[nn + 1][kk + i * 16] = f2bf(v.y);
                T[nn + 2][kk + i * 16] = f2bf(v.z);
                T[nn + 3][kk + i * 16] = f2bf(v.w);
            }
        }
        __syncthreads();
        {
            const int nn = t >> 4;
            const int kk = (t & 15) * 4;
            #pragma unroll
            for (int i = 0; i < 4; ++i) {
                ushort4 o;
                o.x = T[nn + i * 16][kk + 0];
                o.y = T[nn + i * 16][kk + 1];
                o.z = T[nn + i * 16][kk + 2];
                o.w = T[nn + i * 16][kk + 3];
                *(ushort4*)&Wt[(size_t)(nb + nn + i * 16) * H_ + kb + kk] = o;
            }
        }
    }
}

// ---------------------------------------------------------------------------
// Kernel 2 (byte-identical to round-3 measured version):
// C[1024,768] = means_bf16 @ Wt_bf16^T + bias via mfma_f32_16x16x32_bf16.
// 64x64 tile, 256 threads = 4 waves. Ping-pong double-buffered LDS: within
// one inter-sync region reads hit buf[cur], writes hit buf[cur^1] (disjoint)
// -> ONE barrier per K-step (8 total). LDS rows padded to 72 halfs (144 B):
// ds_read_b128-aligned, <=2-way bank aliasing (free, m136).
// A-frag: A[m=lane&15][k=quad*8+j]; B-frag: B[k=quad*8+j][n=lane&15];
// C/D: col=lane&15, row=quad*4+reg (verified layouts, m89/m91).
// ---------------------------------------------------------------------------
__global__ __launch_bounds__(256) void gemm_kernel(
    const unsigned short* __restrict__ A, const unsigned short* __restrict__ Bt,
    const float* __restrict__ bias, float* __restrict__ C)
{
    __shared__ unsigned short As[2][64][72];  // [buf][m][k]
    __shared__ unsigned short Bs[2][64][72];  // [buf][n][k]

    const int t    = threadIdx.x;
    const int lane = t & 63;
    const int wv   = t >> 6;
    const int mrow = lane & 15;
    const int quad = lane >> 4;
    const int m0   = blockIdx.y * 64;
    const int n0   = blockIdx.x * 64;

    // staging map: thread t loads 32 consecutive bytes (16 bf16) of row t>>2;
    // 4 consecutive threads cover one row's 128 B -> fully coalesced.
    const int sr = t >> 2;
    const int sk = (t & 3) * 16;
    const unsigned short* Aptr = A  + (size_t)(m0 + sr) * H_ + sk;
    const unsigned short* Bptr = Bt + (size_t)(n0 + sr) * H_ + sk;

    uint4 a0 = *(const uint4*)Aptr;
    uint4 a1 = *(const uint4*)(Aptr + 8);
    uint4 b0 = *(const uint4*)Bptr;
    uint4 b1 = *(const uint4*)(Bptr + 8);

    *(uint4*)&As[0][sr][sk]     = a0;
    *(uint4*)&As[0][sr][sk + 8] = a1;
    *(uint4*)&Bs[0][sr][sk]     = b0;
    *(uint4*)&Bs[0][sr][sk + 8] = b1;

    f32x4 acc[4] = {};
    int cur = 0;
    __syncthreads();

    for (int k0 = 0; k0 < H_; k0 += 64) {
        const bool more = (k0 + 64 < H_);
        if (more) {  // prefetch next K-tile; latency hidden under MFMA phase
            a0 = *(const uint4*)(Aptr + k0 + 64);
            a1 = *(const uint4*)(Aptr + k0 + 72);
            b0 = *(const uint4*)(Bptr + k0 + 64);
            b1 = *(const uint4*)(Bptr + k0 + 72);
        }

        #pragma unroll
        for (int kk = 0; kk < 2; ++kk) {
            bf16x8 af = *(const bf16x8*)&As[cur][wv * 16 + mrow][kk * 32 + quad * 8];
            #pragma unroll
            for (int t4 = 0; t4 < 4; ++t4) {
                bf16x8 bf = *(const bf16x8*)&Bs[cur][t4 * 16 + mrow][kk * 32 + quad * 8];
                acc[t4] = __builtin_amdgcn_mfma_f32_16x16x32_bf16(af, bf, acc[t4], 0, 0, 0);
            }
        }

        if (more) {  // write OTHER buffer: disjoint from this step's reads
            *(uint4*)&As[cur ^ 1][sr][sk]     = a0;
            *(uint4*)&As[cur ^ 1][sr][sk + 8] = a1;
            *(uint4*)&Bs[cur ^ 1][sr][sk]     = b0;
            *(uint4*)&Bs[cur ^ 1][sr][sk + 8] = b1;
            __syncthreads();   // publish for next step; the ONLY barrier/step
        }
        cur ^= 1;
    }

    #pragma unroll
    for (int t4 = 0; t4 < 4; ++t4) {
        const int col = n0 + t4 * 16 + mrow;
        const float bia = bias[col];
        #pragma unroll
        for (int r = 0; r < 4; ++r) {
            const int rowi = m0 + wv * 16 + quad * 4 + r;
            C[(size_t)rowi * D_ + col] = acc[t4][r] + bia;
        }
    }
}

extern "C" void kernel_launch(void* const* d_in, const int* in_sizes, int n_in,
                              void* d_out, int out_size, void* d_ws, size_t ws_size,
                              hipStream_t stream) {
    const float* bh   = (const float*)d_in[0];
    const float* W    = (const float*)d_in[1];
    const float* bias = (const float*)d_in[2];
    const int*   ids  = (const int*)d_in[3];
    float* out = (float*)d_out;

    unsigned short* means = (unsigned short*)d_ws;                    // 1 MiB
    unsigned short* Wt    = means + (size_t)B_ * P_ * H_;             // 0.75 MiB

    pool_wt_kernel<<<dim3(2 * P_ * B_ + (D_ / 64) * (H_ / 64)), 256, 0, stream>>>(
        bh, ids, W, means, Wt);                                       // 2144 blocks
    gemm_kernel<<<dim3(D_ / 64, (B_ * P_) / 64), 256, 0, stream>>>(   // (12, 16)
        means, Wt, bias, out);
}